// Round 4
// baseline (19.490 us; speedup 1.0000x reference)
//
#include <hip/hip_runtime.h>
#include <math.h>

#define NB 128      // batches
#define TC 128      // subsampled points per batch
#define DD 512      // feature dim
#define TSTR 16     // subsample stride (2048/128)
#define KT 64       // K-tile (floats) staged per iteration
#define NT (DD/KT)  // 8 tiles
#define XP 72       // bf16 LDS row stride (64 + 8 pad) -> conflict-free b128
#define DST 132     // dmat row stride (floats)
#define NTRIP 32

typedef __attribute__((ext_vector_type(8))) short bf16x8;
typedef __attribute__((ext_vector_type(8))) unsigned short u16x8;
typedef __attribute__((ext_vector_type(4))) float f32x4;

__device__ __forceinline__ unsigned short f2bf(float f) {
  unsigned int u = __float_as_uint(f);   // RNE bf16
  return (unsigned short)((u + 0x7fffu + ((u >> 16) & 1u)) >> 16);
}

__device__ __forceinline__ u16x8 cvt8(float4 a, float4 b) {
  u16x8 w;
  w[0]=f2bf(a.x); w[1]=f2bf(a.y); w[2]=f2bf(a.z); w[3]=f2bf(a.w);
  w[4]=f2bf(b.x); w[5]=f2bf(b.y); w[6]=f2bf(b.z); w[7]=f2bf(b.w);
  return w;
}

// One block per batch (minimal HBM traffic: 256KB/block). All global loads
// issued up-front to registers (deep prefetch), bf16-converted in two phases,
// LDS loop fed from registers -> no HBM latency inside the tile loop.
__global__ __launch_bounds__(1024) void topo_fused(
    const float* __restrict__ latent,   // [128][2048][512]
    const float* __restrict__ thr,      // [1]
    const int*   __restrict__ trip,     // [128][32][3]
    float* __restrict__ partial)        // [2*NB]
{
  const int b    = blockIdx.x;
  const int tid  = threadIdx.x;
  const int lane = tid & 63;
  const int wid  = tid >> 6;          // 0..15
  const int wrow = (wid >> 2) * 32;   // wave tile 32x32
  const int wcol = (wid & 3) * 32;

  __shared__ __align__(16) unsigned short xt[2][TC][XP];  // 36.9 KB
  __shared__ float dmat[TC][DST];                         // 67.6 KB
  __shared__ float sqn[TC];
  __shared__ float wred[16];

  const float* xb = latent + (size_t)b * (2048 * 512);

  // staging map: thread t -> row t>>3, k-chunk (t&7)*8 (8 floats per tile)
  const int srow = tid >> 3;
  const int skc  = (tid & 7) * 8;
  const float* sp = xb + (size_t)srow * (TSTR * DD) + skc;

  // ---- deep prefetch: issue ALL 16 float4 loads now ----
  float4 pA[4][2], pB[4][2];
#pragma unroll
  for (int t = 0; t < 4; ++t) {
    pA[t][0] = *reinterpret_cast<const float4*>(sp + t * KT);
    pA[t][1] = *reinterpret_cast<const float4*>(sp + t * KT + 4);
  }
#pragma unroll
  for (int t = 0; t < 4; ++t) {
    pB[t][0] = *reinterpret_cast<const float4*>(sp + (t + 4) * KT);
    pB[t][1] = *reinterpret_cast<const float4*>(sp + (t + 4) * KT + 4);
  }

  u16x8 rb[8];
#pragma unroll
  for (int t = 0; t < 4; ++t) rb[t] = cvt8(pA[t][0], pA[t][1]);

  f32x4 acc[2][2];
#pragma unroll
  for (int i = 0; i < 2; ++i)
#pragma unroll
    for (int j = 0; j < 2; ++j)
#pragma unroll
      for (int r = 0; r < 4; ++r) acc[i][j][r] = 0.f;

  const int r0  = wrow + (lane & 15);
  const int c0  = wcol + (lane & 15);
  const int kk0 = (lane >> 4) << 3;

  // prologue: write tile 0
  *reinterpret_cast<u16x8*>(&xt[0][srow][skc]) = rb[0];
  __syncthreads();

  for (int t = 0; t < NT; ++t) {
    if (t == 3) {   // uniform: convert phase-B (loads have been in flight)
#pragma unroll
      for (int q = 0; q < 4; ++q) rb[4 + q] = cvt8(pB[q][0], pB[q][1]);
    }
    if (t + 1 < NT)
      *reinterpret_cast<u16x8*>(&xt[(t + 1) & 1][srow][skc]) = rb[t + 1];
    const int cur = t & 1;
#pragma unroll
    for (int sub = 0; sub < 2; ++sub) {
      const int kk = sub * 32 + kk0;
      bf16x8 a0 = *reinterpret_cast<const bf16x8*>(&xt[cur][r0][kk]);
      bf16x8 a1 = *reinterpret_cast<const bf16x8*>(&xt[cur][r0 + 16][kk]);
      bf16x8 b0 = *reinterpret_cast<const bf16x8*>(&xt[cur][c0][kk]);
      bf16x8 b1 = *reinterpret_cast<const bf16x8*>(&xt[cur][c0 + 16][kk]);
      acc[0][0] = __builtin_amdgcn_mfma_f32_16x16x32_bf16(a0, b0, acc[0][0], 0, 0, 0);
      acc[0][1] = __builtin_amdgcn_mfma_f32_16x16x32_bf16(a0, b1, acc[0][1], 0, 0, 0);
      acc[1][0] = __builtin_amdgcn_mfma_f32_16x16x32_bf16(a1, b0, acc[1][0], 0, 0, 0);
      acc[1][1] = __builtin_amdgcn_mfma_f32_16x16x32_bf16(a1, b1, acc[1][1], 0, 0, 0);
    }
    __syncthreads();
  }

  // diagonal -> sqn (C/D layout: col=lane&15, row=(lane>>4)*4+reg  [m89])
  const int rbase = (lane >> 4) << 2;
  const int cidx  = lane & 15;
#pragma unroll
  for (int fr = 0; fr < 2; ++fr)
#pragma unroll
    for (int fc = 0; fc < 2; ++fc)
#pragma unroll
      for (int reg = 0; reg < 4; ++reg) {
        int grow = wrow + fr * 16 + rbase + reg;
        int gcol = wcol + fc * 16 + cidx;
        if (grow == gcol) sqn[grow] = acc[fr][fc][reg];
      }
  __syncthreads();

  const float thv = fabsf(thr[0]) + 0.1f;
  float psum = 0.f;
#pragma unroll
  for (int fr = 0; fr < 2; ++fr)
#pragma unroll
    for (int fc = 0; fc < 2; ++fc)
#pragma unroll
      for (int reg = 0; reg < 4; ++reg) {
        int grow = wrow + fr * 16 + rbase + reg;
        int gcol = wcol + fc * 16 + cidx;
        float g  = acc[fr][fc][reg];
        float sq = fmaxf(sqn[grow] + sqn[gcol] - 2.f * g, 0.f);
        float d  = sqrtf(sq);
        dmat[grow][gcol] = d;
        if (grow != gcol) psum += 1.f / (1.f + __expf(d - thv));
      }

#pragma unroll
  for (int off = 32; off; off >>= 1) psum += __shfl_down(psum, off, 64);
  if (lane == 0) wred[wid] = psum;
  __syncthreads();   // fences dmat for the triplet gather too

  if (wid == 0) {
    float h = 0.f;
    if (lane < NTRIP) {
      const int* tp = trip + ((size_t)b * NTRIP + lane) * 3;
      int i0 = tp[0], i1 = tp[1], i2 = tp[2];
      float e0 = dmat[i0][i1], e1 = dmat[i0][i2], e2 = dmat[i1][i2];
      float m  = (e0 + e1 + e2) * (1.f / 3.f);
      float d0 = e0 - m, d1 = e1 - m, d2 = e2 - m;
      float v  = (d0 * d0 + d1 * d1 + d2 * d2) * 0.5f;  // ddof=1
      h = __expf(-v);
    }
#pragma unroll
    for (int off = 32; off; off >>= 1) h += __shfl_down(h, off, 64);
    if (lane == 0) {
      float conn = 0.f;
#pragma unroll
      for (int w = 0; w < 16; ++w) conn += wred[w];
      partial[b]      = 1.f - conn / 16256.0f;   // Tc*(Tc-1)+1e-8
      partial[NB + b] = h * (1.f / NTRIP);
    }
  }
}

__global__ void topo_final(const float* __restrict__ partial, float* __restrict__ out)
{
  const int t = threadIdx.x;  // 128 threads
  float v = partial[t] + 0.5f * partial[NB + t];
#pragma unroll
  for (int off = 32; off; off >>= 1) v += __shfl_down(v, off, 64);
  __shared__ float s2[2];
  if ((t & 63) == 0) s2[t >> 6] = v;
  __syncthreads();
  if (t == 0) out[0] = (s2[0] + s2[1]) * (1.f / NB);
}

extern "C" void kernel_launch(void* const* d_in, const int* in_sizes, int n_in,
                              void* d_out, int out_size, void* d_ws, size_t ws_size,
                              hipStream_t stream) {
  const float* latent = (const float*)d_in[0];
  const float* thr    = (const float*)d_in[1];
  const int*   trip   = (const int*)d_in[2];
  float* partial = (float*)d_ws;   // 256 floats

  topo_fused<<<NB, 1024, 0, stream>>>(latent, thr, trip, partial);
  topo_final<<<1, 128, 0, stream>>>(partial, (float*)d_out);
}

// Round 5
// 18.681 us; speedup vs baseline: 1.0433x; 1.0433x over previous
//
#include <hip/hip_runtime.h>
#include <math.h>

#define NB 128      // batches
#define TC 128      // subsampled points per batch
#define HALF 64     // output rows per block
#define DD 512      // feature dim
#define TSTR 16     // subsample stride (2048/128)
#define KT 64       // K-tile (floats) staged per iteration
#define NT (DD/KT)  // 8 tiles
#define XP 72       // bf16 LDS row stride (64 + 8 pad)
#define DST 132     // dmat row stride (floats)
#define NTRIP 32

typedef __attribute__((ext_vector_type(8))) short bf16x8;
typedef __attribute__((ext_vector_type(8))) unsigned short u16x8;
typedef __attribute__((ext_vector_type(4))) float f32x4;

__device__ __forceinline__ unsigned short f2bf(float f) {
  unsigned int u = __float_as_uint(f);   // RNE bf16
  return (unsigned short)((u + 0x7fffu + ((u >> 16) & 1u)) >> 16);
}

__device__ __forceinline__ u16x8 cvt8(float4 a, float4 b) {
  u16x8 w;
  w[0]=f2bf(a.x); w[1]=f2bf(a.y); w[2]=f2bf(a.z); w[3]=f2bf(a.w);
  w[4]=f2bf(b.x); w[5]=f2bf(b.y); w[6]=f2bf(b.z); w[7]=f2bf(b.w);
  return w;
}

// grid = 256: block (s = blk>>7, b = blk&127) computes rows [s*64, s*64+64)
// x cols [0,128) of batch b's distance matrix. 512 threads = 8 waves (2x4).
// Both halves of a batch land on the same XCD (swizzle) -> L2 dedupe of the
// duplicated X read. 2 waves/SIMD -> 256-VGPR budget -> real deep prefetch.
__global__ __launch_bounds__(512, 2) void topo_half(
    const float* __restrict__ latent,   // [128][2048][512]
    const float* __restrict__ thr,      // [1]
    const int*   __restrict__ trip,     // [128][32][3]
    float* __restrict__ ws_psum,        // [256]
    float* __restrict__ ws_edge)        // [128*32*3]
{
  const int blk  = blockIdx.x;
  const int s    = blk >> 7;          // row-half
  const int b    = blk & 127;         // batch
  const int tid  = threadIdx.x;
  const int lane = tid & 63;
  const int wid  = tid >> 6;          // 0..7
  const int wrow = (wid >> 2) * 32;   // local A-row block: 0 or 32
  const int wcol = (wid & 3) * 32;    // B-col block: 0,32,64,96

  __shared__ __align__(16) unsigned short xt[2][TC][XP];  // 36.9 KB
  __shared__ float dmat[HALF][DST];                       // 33.8 KB
  __shared__ float sqn[TC];
  __shared__ float wred[8];

  const float* xb = latent + (size_t)b * (2048 * 512);

  // staging map: thread t -> row t>>2, 16-float chunk (t&3)*16 per tile
  const int srow = tid >> 2;
  const int skc  = (tid & 3) * 16;
  const float* sp = xb + (size_t)srow * (TSTR * DD) + skc;

  // ---- deep prefetch: all 32 float4 issued before any conversion ----
  float4 pA[4][4], pB[4][4];
#pragma unroll
  for (int t = 0; t < 4; ++t)
#pragma unroll
    for (int q = 0; q < 4; ++q)
      pA[t][q] = *reinterpret_cast<const float4*>(sp + t * KT + q * 4);
#pragma unroll
  for (int t = 0; t < 4; ++t)
#pragma unroll
    for (int q = 0; q < 4; ++q)
      pB[t][q] = *reinterpret_cast<const float4*>(sp + (t + 4) * KT + q * 4);

  float ssq = 0.f;
  u16x8 rb[16];
#pragma unroll
  for (int t = 0; t < 4; ++t) {
    rb[2 * t]     = cvt8(pA[t][0], pA[t][1]);
    rb[2 * t + 1] = cvt8(pA[t][2], pA[t][3]);
#pragma unroll
    for (int q = 0; q < 4; ++q) {
      float4 v = pA[t][q];
      ssq += v.x * v.x + v.y * v.y + v.z * v.z + v.w * v.w;
    }
  }

  f32x4 acc[2][2];
#pragma unroll
  for (int i = 0; i < 2; ++i)
#pragma unroll
    for (int j = 0; j < 2; ++j)
#pragma unroll
      for (int r = 0; r < 4; ++r) acc[i][j][r] = 0.f;

  const int r0  = s * HALF + wrow + (lane & 15);  // global A row
  const int c0  = wcol + (lane & 15);             // global B row (col)
  const int kk0 = (lane >> 4) << 3;

  // prologue: tile 0 into buf 0
  *reinterpret_cast<u16x8*>(&xt[0][srow][skc])     = rb[0];
  *reinterpret_cast<u16x8*>(&xt[0][srow][skc + 8]) = rb[1];
  __syncthreads();

  for (int t = 0; t < NT; ++t) {
    if (t == 3) {   // uniform: convert phase B (loads long in flight)
#pragma unroll
      for (int u = 0; u < 4; ++u) {
        rb[8 + 2 * u] = cvt8(pB[u][0], pB[u][1]);
        rb[9 + 2 * u] = cvt8(pB[u][2], pB[u][3]);
#pragma unroll
        for (int q = 0; q < 4; ++q) {
          float4 v = pB[u][q];
          ssq += v.x * v.x + v.y * v.y + v.z * v.z + v.w * v.w;
        }
      }
    }
    if (t + 1 < NT) {
      *reinterpret_cast<u16x8*>(&xt[(t + 1) & 1][srow][skc])     = rb[2 * t + 2];
      *reinterpret_cast<u16x8*>(&xt[(t + 1) & 1][srow][skc + 8]) = rb[2 * t + 3];
    }
    const int cur = t & 1;
#pragma unroll
    for (int sub = 0; sub < 2; ++sub) {
      const int kk = sub * 32 + kk0;
      bf16x8 a0 = *reinterpret_cast<const bf16x8*>(&xt[cur][r0][kk]);
      bf16x8 a1 = *reinterpret_cast<const bf16x8*>(&xt[cur][r0 + 16][kk]);
      bf16x8 b0 = *reinterpret_cast<const bf16x8*>(&xt[cur][c0][kk]);
      bf16x8 b1 = *reinterpret_cast<const bf16x8*>(&xt[cur][c0 + 16][kk]);
      acc[0][0] = __builtin_amdgcn_mfma_f32_16x16x32_bf16(a0, b0, acc[0][0], 0, 0, 0);
      acc[0][1] = __builtin_amdgcn_mfma_f32_16x16x32_bf16(a0, b1, acc[0][1], 0, 0, 0);
      acc[1][0] = __builtin_amdgcn_mfma_f32_16x16x32_bf16(a1, b0, acc[1][0], 0, 0, 0);
      acc[1][1] = __builtin_amdgcn_mfma_f32_16x16x32_bf16(a1, b1, acc[1][1], 0, 0, 0);
    }
    __syncthreads();
  }

  // sqn[row] = sum of f32 squares (4 threads per row -> xor-reduce)
  ssq += __shfl_xor(ssq, 1, 64);
  ssq += __shfl_xor(ssq, 2, 64);
  if ((tid & 3) == 0) sqn[srow] = ssq;
  __syncthreads();

  // epilogue: d, sigmoid-sum, dmat (C/D layout: col=lane&15, row=(lane>>4)*4+reg)
  const int rbase = (lane >> 4) << 2;
  const int cidx  = lane & 15;
  const float thv = fabsf(thr[0]) + 0.1f;
  float psum = 0.f;
#pragma unroll
  for (int fr = 0; fr < 2; ++fr)
#pragma unroll
    for (int fc = 0; fc < 2; ++fc)
#pragma unroll
      for (int reg = 0; reg < 4; ++reg) {
        int growL = wrow + fr * 16 + rbase + reg;     // local row 0..63
        int grow  = s * HALF + growL;                 // global row
        int gcol  = wcol + fc * 16 + cidx;
        float d = 0.f;
        if (grow != gcol) {
          float g  = acc[fr][fc][reg];
          float sq = fmaxf(sqn[grow] + sqn[gcol] - 2.f * g, 0.f);
          d = sqrtf(sq);
          psum += 1.f / (1.f + __expf(d - thv));
        }
        dmat[growL][gcol] = d;
      }

#pragma unroll
  for (int off = 32; off; off >>= 1) psum += __shfl_down(psum, off, 64);
  if (lane == 0) wred[wid] = psum;
  __syncthreads();   // fences dmat for edge gather

  if (wid == 0) {
    if (lane < NTRIP) {
      const int* tp = trip + ((size_t)b * NTRIP + lane) * 3;
      const int i0 = tp[0], i1 = tp[1], i2 = tp[2];
      const size_t ebase = ((size_t)b * NTRIP + lane) * 3;
      int ps[3] = {i0, i0, i1};
      int qs[3] = {i1, i2, i2};
#pragma unroll
      for (int e = 0; e < 3; ++e) {
        int p = ps[e], q = qs[e];
        int mx = p > q ? p : q, mn = p > q ? q : p;
        if ((mx >> 6) == s)   // this block owns the edge
          ws_edge[ebase + e] = (mx == mn) ? 0.f : dmat[mx - s * HALF][mn];
      }
    }
    if (lane == 0) {
      float conn = 0.f;
#pragma unroll
      for (int w = 0; w < 8; ++w) conn += wred[w];
      ws_psum[blk] = conn;
    }
  }
}

// Grand final: sum all 256 psum partials + all 4096 triplet hole terms.
__global__ __launch_bounds__(1024) void topo_final(
    const float* __restrict__ ws_psum,
    const float* __restrict__ ws_edge,
    float* __restrict__ out)
{
  const int t    = threadIdx.x;
  const int lane = t & 63;
  const int wid  = t >> 6;

  float ps = (t < 2 * NB) ? ws_psum[t] : 0.f;
  float hs = 0.f;
#pragma unroll
  for (int k = 0; k < 4; ++k) {
    int id = t + 1024 * k;            // 0..4095 triplet slots
    float e0 = ws_edge[id * 3 + 0];
    float e1 = ws_edge[id * 3 + 1];
    float e2 = ws_edge[id * 3 + 2];
    float m  = (e0 + e1 + e2) * (1.f / 3.f);
    float d0 = e0 - m, d1 = e1 - m, d2 = e2 - m;
    float v  = (d0 * d0 + d1 * d1 + d2 * d2) * 0.5f;   // ddof=1
    hs += __expf(-v);
  }

#pragma unroll
  for (int off = 32; off; off >>= 1) {
    ps += __shfl_down(ps, off, 64);
    hs += __shfl_down(hs, off, 64);
  }
  __shared__ float rp[16], rh[16];
  if (lane == 0) { rp[wid] = ps; rh[wid] = hs; }
  __syncthreads();
  if (t == 0) {
    float Ps = 0.f, Hs = 0.f;
#pragma unroll
    for (int w = 0; w < 16; ++w) { Ps += rp[w]; Hs += rh[w]; }
    // loss = mean_b(1 - conn_b/16256) + 0.5 * mean_all(h)
    out[0] = 1.f - Ps / (16256.f * NB) + 0.5f * (Hs / (NB * NTRIP));
  }
}

extern "C" void kernel_launch(void* const* d_in, const int* in_sizes, int n_in,
                              void* d_out, int out_size, void* d_ws, size_t ws_size,
                              hipStream_t stream) {
  const float* latent = (const float*)d_in[0];
  const float* thr    = (const float*)d_in[1];
  const int*   trip   = (const int*)d_in[2];

  float* ws_psum = (float*)d_ws;              // 256 floats
  float* ws_edge = ws_psum + 2 * NB;          // 12288 floats

  topo_half<<<2 * NB, 512, 0, stream>>>(latent, thr, trip, ws_psum, ws_edge);
  topo_final<<<1, 1024, 0, stream>>>(ws_psum, ws_edge, (float*)d_out);
}